// Round 4
// baseline (1336.944 us; speedup 1.0000x reference)
//
#include <hip/hip_runtime.h>

// FK object-translation scan, round 3: wave-per-batch.
// 512 blocks x 64 lanes; each wave owns one batch chain. Lanes cooperatively
// stage 256-step input chunks into padded LDS (coalesced), then the wave
// walks the 256 steps with uniform scalar compute (all lanes replicate).
// State machine lives in SGPRs via readfirstlane -> s_cbranch skips.
// Float carry is W = dir_local * dist (product trick): grab step does
// W = R^T (pos - h) with no sqrt/rcp on the chain; pos = h + R W.
// Semantics match the reference up to ~1e-7 rel rounding (absmax margin
// was 0.5 vs threshold 3.18 with exact math).

#define CT 256

__global__ __launch_bounds__(64) void fk_scan_wave(
    const float* __restrict__ prob,   // (B,T,2)
    const float* __restrict__ hands,  // (B,T,2,3)
    const float* __restrict__ rotm,   // (B,T,3,3)
    const float* __restrict__ tinit,  // (B,3)
    float* __restrict__ out,          // (B,T,3)
    int B, int T)
{
    __shared__ __align__(16) float sP[CT * 2];   // prob, packed
    __shared__ __align__(16) float sH[CT * 8];   // hands, padded 6->8
    __shared__ __align__(16) float sR[CT * 12];  // rotm,  padded 9->12

    const int b    = blockIdx.x;
    const int lane = threadIdx.x;

    const float* prB = prob  + (size_t)b * T * 2;
    const float* hdB = hands + (size_t)b * T * 6;
    const float* rmB = rotm  + (size_t)b * T * 9;
    float*       obB = out   + (size_t)b * T * 3;

    // carry (lane-replicated, identical across the wave)
    float px = tinit[3*b+0], py = tinit[3*b+1], pz = tinit[3*b+2];
    float Wx = 0.f, Wy = 0.f, Wz = 0.f;   // dir_local * dist
    int   cur = -1;
    int   prev_l = 0, prev_r = 0;

    for (int t0 = 0; t0 < T; t0 += CT) {
        const int n = (T - t0 < CT) ? (T - t0) : CT;

        // ---- coalesced staging into padded LDS ----
        for (int i = lane; i < n * 2; i += 64)
            sP[i] = prB[(size_t)t0 * 2 + i];
        for (int i = lane; i < n * 6; i += 64) {
            int s = i / 6, c = i - 6 * s;
            sH[8 * s + c] = hdB[(size_t)t0 * 6 + i];
        }
        for (int i = lane; i < n * 9; i += 64) {
            int s = i / 9, c = i - 9 * s;
            sR[12 * s + c] = rmB[(size_t)t0 * 9 + i];
        }
        __syncthreads();

        for (int k = 0; k < n; ++k) {
            const int t = t0 + k;
            const float p0 = sP[2*k+0];
            const float p1 = sP[2*k+1];
            // hoist contact bits to SGPRs -> uniform (s_cbranch) control flow
            const int rl = __builtin_amdgcn_readfirstlane(p0 > 0.5f ? 1 : 0);
            const int rr = __builtin_amdgcn_readfirstlane(p1 > 0.5f ? 1 : 0);
            const int nz  = (t != 0) ? 1 : 0;
            const int l_c = rl & nz;
            const int r_c = rr & nz;
            const int l_s = rl & (prev_l ^ 1) & nz;
            const int r_s = rr & (prev_r ^ 1) & nz;
            prev_l = rl; prev_r = rr;

            const int nw   = l_s ? 0 : (r_s ? 1 : -1);
            const int hasc = ((cur == 0) & l_c) | ((cur == 1) & r_c);
            const int haso = ((cur == 0) & r_c) | ((cur == 1) & l_c);
            const int grab = (nw != -1) | ((hasc ^ 1) & haso);
            const int new_cur = grab ? ((nw != -1) ? nw : (1 - cur))
                                     : (((hasc ^ 1) & (cur != -1)) ? -1 : cur);

            if (new_cur != -1) {           // attached this step (grab implies this)
                const float h0x = sH[8*k+0], h0y = sH[8*k+1], h0z = sH[8*k+2];
                const float h1x = sH[8*k+3], h1y = sH[8*k+4], h1z = sH[8*k+5];
                const float R0 = sR[12*k+0], R1 = sR[12*k+1], R2 = sR[12*k+2];
                const float R3 = sR[12*k+3], R4 = sR[12*k+4], R5 = sR[12*k+5];
                const float R6 = sR[12*k+6], R7 = sR[12*k+7], R8 = sR[12*k+8];
                // at grab, vec-hand == new hand (new_cur == cur_grab), so one select
                const float hx = new_cur ? h1x : h0x;
                const float hy = new_cur ? h1y : h0y;
                const float hz = new_cur ? h1z : h0z;

                if (grab) {
                    const float vx = px - hx, vy = py - hy, vz = pz - hz;
                    const float d2 = vx*vx + vy*vy + vz*vz;
                    if (d2 > 1e-12f) {     // valid: W = R^T vec  (= R^T u * d)
                        Wx = R0*vx + R3*vy + R6*vz;
                        Wy = R1*vx + R4*vy + R7*vz;
                        Wz = R2*vx + R5*vy + R8*vz;
                    } else {               // degenerate: u = z, dist = 0.1
                        Wx = 0.1f * R6; Wy = 0.1f * R7; Wz = 0.1f * R8;
                    }
                }
                px = hx + (R0*Wx + R1*Wy + R2*Wz);
                py = hy + (R3*Wx + R4*Wy + R5*Wz);
                pz = hz + (R6*Wx + R7*Wy + R8*Wz);
            }
            cur = new_cur;

            if (lane == 0) {
                obB[3*(size_t)t + 0] = px;
                obB[3*(size_t)t + 1] = py;
                obB[3*(size_t)t + 2] = pz;
            }
        }
        __syncthreads();   // all reads of this chunk done before next staging
    }
}

extern "C" void kernel_launch(void* const* d_in, const int* in_sizes, int n_in,
                              void* d_out, int out_size, void* d_ws, size_t ws_size,
                              hipStream_t stream) {
    const float* prob  = (const float*)d_in[0];  // (B,T,2)
    const float* hands = (const float*)d_in[1];  // (B,T,2,3)
    const float* rotm  = (const float*)d_in[2];  // (B,T,3,3)
    const float* tinit = (const float*)d_in[3];  // (B,3)
    float* out = (float*)d_out;

    const int B = in_sizes[3] / 3;
    const int T = in_sizes[0] / (B * 2);

    hipLaunchKernelGGL(fk_scan_wave, dim3(B), dim3(64), 0, stream,
                       prob, hands, rotm, tinit, out, B, T);
}

// Round 5
// 104.385 us; speedup vs baseline: 12.8078x; 12.8078x over previous
//
#include <hip/hip_runtime.h>

// FK object-translation scan, round 5: T-parallel via function composition.
// One wave per batch. T=4096 split into 64 chunks of 64 steps (one per lane).
//  P1: pack contact bits; per-lane compose the 3-state FSM maps (6-bit packed).
//  FSM Kogge-Stone scan -> each lane's exact entry state cur_in.
//  P2: per-lane compose the affine float map on (p, W=dir*dist) in R^6.
//      grab: W'=R^T(p-h) [p'~=p, RR^T~=I approx in composition only];
//      attach: p'=h+RW; detach: id.
//  Affine Kogge-Stone scan (42-float maps) -> exact-ish entry (p_in, W_in).
//  P3: re-run exact recurrence per-lane from entry state, write outputs.
// Discrete trajectory is bit-exact (FSM is float-independent); float error is
// composition reassociation ~1e-3 vs threshold 3.18 (round-3 margin: 0.5).

#define FSM_ID 0x24  // identity map: 0->0, 1->1, 2->2 (2 bits each)

__device__ __forceinline__ int fsm_compose(int f, int g) {
    // apply g first, then f
    int r0 = (f >> (((g     ) & 3) << 1)) & 3;
    int r1 = (f >> (((g >> 2) & 3) << 1)) & 3;
    int r2 = (f >> (((g >> 4) & 3) << 1)) & 3;
    return r0 | (r1 << 2) | (r2 << 4);
}

// affine map on (p,W): layout A[0..8] B[9..17] C[18..26] D[27..35] e[36..38] f[39..41]
__device__ __forceinline__ void aff_identity(float* m) {
    #pragma unroll
    for (int i = 0; i < 42; ++i) m[i] = 0.f;
    m[0] = m[4] = m[8] = 1.f;
    m[27] = m[31] = m[35] = 1.f;
}

__device__ __forceinline__ void aff_compose(float* L, const float* E) {
    // L <- L o E  (apply E first, then L)
    float n[42];
    #pragma unroll
    for (int i = 0; i < 3; ++i) {
        #pragma unroll
        for (int j = 0; j < 3; ++j) {
            float a = 0.f, b = 0.f, c = 0.f, d = 0.f;
            #pragma unroll
            for (int k = 0; k < 3; ++k) {
                const float La = L[3*i+k],    Lb = L[9+3*i+k];
                const float Lc = L[18+3*i+k], Ld = L[27+3*i+k];
                a += La * E[3*k+j]    + Lb * E[18+3*k+j];
                b += La * E[9+3*k+j]  + Lb * E[27+3*k+j];
                c += Lc * E[3*k+j]    + Ld * E[18+3*k+j];
                d += Lc * E[9+3*k+j]  + Ld * E[27+3*k+j];
            }
            n[3*i+j] = a; n[9+3*i+j] = b; n[18+3*i+j] = c; n[27+3*i+j] = d;
        }
        float ee = L[36+i], ff = L[39+i];
        #pragma unroll
        for (int k = 0; k < 3; ++k) {
            ee += L[3*i+k]    * E[36+k] + L[9+3*i+k]  * E[39+k];
            ff += L[18+3*i+k] * E[36+k] + L[27+3*i+k] * E[39+k];
        }
        n[36+i] = ee; n[39+i] = ff;
    }
    #pragma unroll
    for (int i = 0; i < 42; ++i) L[i] = n[i];
}

__global__ __launch_bounds__(64) void fk_scan_par(
    const float* __restrict__ prob,   // (B,4096,2)
    const float* __restrict__ hands,  // (B,4096,2,3)
    const float* __restrict__ rotm,   // (B,4096,3,3)
    const float* __restrict__ tinit,  // (B,3)
    float* __restrict__ out)          // (B,4096,3)
{
    const int b    = blockIdx.x;
    const int lane = threadIdx.x;     // 0..63, owns steps [64*lane, 64*lane+64)
    const int T    = 4096;

    const float*  prB = prob  + (size_t)b * T * 2;
    const float*  hdB = hands + (size_t)b * T * 6;
    const float*  rmB = rotm  + (size_t)b * T * 9;
    float*        obB = out   + (size_t)b * T * 3;

    const float4* pr4 = (const float4*)prB + lane * 32;   // 64 steps * 2 / 4
    const float2* hd2 = (const float2*)hdB + lane * 192;  // 64 steps * 6 / 2
    const float4* rm4 = (const float4*)rmB + lane * 144;  // 64 steps * 9 / 4
    float4*       ob4 = (float4*)obB       + lane * 48;   // 64 steps * 3 / 4

    // ---------------- P1: pack contact bits (bit k = lane-local step k) ----
    unsigned lcLo = 0, lcHi = 0, rcLo = 0, rcHi = 0;
    #pragma unroll
    for (int i = 0; i < 16; ++i) {
        float4 v = pr4[i];
        lcLo |= (unsigned)(v.x > 0.5f) << (2*i);
        rcLo |= (unsigned)(v.y > 0.5f) << (2*i);
        lcLo |= (unsigned)(v.z > 0.5f) << (2*i+1);
        rcLo |= (unsigned)(v.w > 0.5f) << (2*i+1);
    }
    #pragma unroll
    for (int i = 16; i < 32; ++i) {
        float4 v = pr4[i];
        lcHi |= (unsigned)(v.x > 0.5f) << (2*i-32);
        rcHi |= (unsigned)(v.y > 0.5f) << (2*i-32);
        lcHi |= (unsigned)(v.z > 0.5f) << (2*i-31);
        rcHi |= (unsigned)(v.w > 0.5f) << (2*i-31);
    }

    // start bits: ls = lc & ~lc_prev  (carry last bit across lanes)
    unsigned plc = (unsigned)__shfl_up((int)lcHi, 1);
    unsigned prc = (unsigned)__shfl_up((int)rcHi, 1);
    unsigned cLc = lane ? (plc >> 31) & 1u : 0u;
    unsigned cRc = lane ? (prc >> 31) & 1u : 0u;
    unsigned lsLo = lcLo & ~((lcLo << 1) | cLc);
    unsigned lsHi = lcHi & ~((lcHi << 1) | (lcLo >> 31));
    unsigned rsLo = rcLo & ~((rcLo << 1) | cRc);
    unsigned rsHi = rcHi & ~((rcHi << 1) | (rcLo >> 31));
    // global t=0: all flags forced false (reference concat of t0=False)
    if (lane == 0) { lcLo &= ~1u; rcLo &= ~1u; lsLo &= ~1u; rsLo &= ~1u; }

    // ---------------- P1b: compose FSM maps over this lane's 64 steps ------
    int M = FSM_ID;
    #pragma unroll
    for (int k = 0; k < 64; ++k) {
        unsigned lc, rc, ls, rs;
        if (k < 32) {
            lc = (lcLo >> k) & 1u; rc = (rcLo >> k) & 1u;
            ls = (lsLo >> k) & 1u; rs = (rsLo >> k) & 1u;
        } else {
            lc = (lcHi >> (k-32)) & 1u; rc = (rcHi >> (k-32)) & 1u;
            ls = (lsHi >> (k-32)) & 1u; rs = (rsHi >> (k-32)) & 1u;
        }
        const int nwi = (int)(ls | rs);
        const int nwe = ls ? 1 : 2;                 // encoded new hand (+1)
        const int e0  = lc ? 1 : (rc ? 2 : 0);      // image of cur=0
        const int e1  = rc ? 2 : (lc ? 1 : 0);      // image of cur=1
        const int mt  = nwi ? nwe * 0x15 : ((e0 << 2) | (e1 << 4)); // img(-1)=0
        M = fsm_compose(mt, M);
    }
    // inclusive Kogge-Stone scan of FSM maps
    #pragma unroll
    for (int d = 1; d < 64; d <<= 1) {
        int v = __shfl_up(M, d);
        int c = fsm_compose(M, v);
        M = (lane >= d) ? c : M;
    }
    int Mexc = __shfl_up(M, 1);
    if (lane == 0) Mexc = FSM_ID;
    const int s_in = Mexc & 3;   // apply exclusive map to initial state 0 (=cur -1)

    // ---------------- P2: compose affine float maps ------------------------
    float Mv[42];
    aff_identity(Mv);
    float* Am = Mv;      float* Bm = Mv + 9;
    float* Cm = Mv + 18; float* Dm = Mv + 27;
    float* ev = Mv + 36; float* fv = Mv + 39;

    int s = s_in;
    for (int g = 0; g < 16; ++g) {
        float rbuf[36];
        #pragma unroll
        for (int j = 0; j < 9; ++j) {
            float4 v = rm4[g*9 + j];
            rbuf[4*j] = v.x; rbuf[4*j+1] = v.y; rbuf[4*j+2] = v.z; rbuf[4*j+3] = v.w;
        }
        #pragma unroll
        for (int j = 0; j < 4; ++j) {
            const int k = g*4 + j;
            const unsigned sh = (unsigned)k & 31u;
            const unsigned lc = ((k < 32 ? lcLo : lcHi) >> sh) & 1u;
            const unsigned rc = ((k < 32 ? rcLo : rcHi) >> sh) & 1u;
            const unsigned ls = ((k < 32 ? lsLo : lsHi) >> sh) & 1u;
            const unsigned rs = ((k < 32 ? rsLo : rsHi) >> sh) & 1u;
            const int nwi  = (int)(ls | rs);
            const int c1   = (s == 1);
            const int c2   = (s == 2);
            const int hasc = (c1 & (int)lc) | (c2 & (int)rc);
            const int haso = (c1 & (int)rc) | (c2 & (int)lc);
            const int grab = nwi | ((hasc ^ 1) & haso);
            const int gi   = nwi ? (ls ? 0 : 1) : c1;   // hand idx when grabbing
            const int new_s = grab ? gi + 1 : (hasc ? s : 0);

            const float* Rk = rbuf + 9*j;
            if (grab) {
                float2 ha = hd2[k*3+0], hb = hd2[k*3+1], hcp = hd2[k*3+2];
                const float hx = gi ? hb.y  : ha.x;
                const float hy = gi ? hcp.x : ha.y;
                const float hz = gi ? hcp.y : hb.x;
                // (C,D,f) <- R^T o (A,B,e-h);  p-part approximated unchanged
                const float ex = ev[0]-hx, ey = ev[1]-hy, ez = ev[2]-hz;
                float t[9], u[9];
                #pragma unroll
                for (int i = 0; i < 3; ++i)
                    #pragma unroll
                    for (int c = 0; c < 3; ++c) {
                        t[3*i+c] = Rk[i]*Am[c] + Rk[3+i]*Am[3+c] + Rk[6+i]*Am[6+c];
                        u[3*i+c] = Rk[i]*Bm[c] + Rk[3+i]*Bm[3+c] + Rk[6+i]*Bm[6+c];
                    }
                const float w0 = Rk[0]*ex + Rk[3]*ey + Rk[6]*ez;
                const float w1 = Rk[1]*ex + Rk[4]*ey + Rk[7]*ez;
                const float w2 = Rk[2]*ex + Rk[5]*ey + Rk[8]*ez;
                #pragma unroll
                for (int i = 0; i < 9; ++i) { Cm[i] = t[i]; Dm[i] = u[i]; }
                fv[0] = w0; fv[1] = w1; fv[2] = w2;
            } else if (new_s) {
                float2 ha = hd2[k*3+0], hb = hd2[k*3+1], hcp = hd2[k*3+2];
                const int ci = new_s - 1;
                const float hx = ci ? hb.y  : ha.x;
                const float hy = ci ? hcp.x : ha.y;
                const float hz = ci ? hcp.y : hb.x;
                // (A,B,e) <- h + R o (C,D,f)
                float t[9], u[9];
                #pragma unroll
                for (int i = 0; i < 3; ++i)
                    #pragma unroll
                    for (int c = 0; c < 3; ++c) {
                        t[3*i+c] = Rk[3*i]*Cm[c] + Rk[3*i+1]*Cm[3+c] + Rk[3*i+2]*Cm[6+c];
                        u[3*i+c] = Rk[3*i]*Dm[c] + Rk[3*i+1]*Dm[3+c] + Rk[3*i+2]*Dm[6+c];
                    }
                const float e0_ = hx + Rk[0]*fv[0] + Rk[1]*fv[1] + Rk[2]*fv[2];
                const float e1_ = hy + Rk[3]*fv[0] + Rk[4]*fv[1] + Rk[5]*fv[2];
                const float e2_ = hz + Rk[6]*fv[0] + Rk[7]*fv[1] + Rk[8]*fv[2];
                #pragma unroll
                for (int i = 0; i < 9; ++i) { Am[i] = t[i]; Bm[i] = u[i]; }
                ev[0] = e0_; ev[1] = e1_; ev[2] = e2_;
            }
            s = new_s;
        }
    }

    // ---------------- affine Kogge-Stone scan ------------------------------
    #pragma unroll 1
    for (int d = 1; d < 64; d <<= 1) {
        float Ev[42];
        #pragma unroll
        for (int i = 0; i < 42; ++i) Ev[i] = __shfl_up(Mv[i], d);
        float Sv[42];
        #pragma unroll
        for (int i = 0; i < 42; ++i) Sv[i] = Mv[i];
        aff_compose(Sv, Ev);
        const bool act = (lane >= d);
        #pragma unroll
        for (int i = 0; i < 42; ++i) Mv[i] = act ? Sv[i] : Mv[i];
    }

    // exclusive shift + apply to (p0, W0=0): only A, C, e, f needed
    const float p0x = tinit[3*b+0], p0y = tinit[3*b+1], p0z = tinit[3*b+2];
    float pA[9], pC[9], pe[3], pf[3];
    #pragma unroll
    for (int i = 0; i < 9; ++i) {
        pA[i] = __shfl_up(Mv[i],      1);
        pC[i] = __shfl_up(Mv[18 + i], 1);
    }
    #pragma unroll
    for (int i = 0; i < 3; ++i) {
        pe[i] = __shfl_up(Mv[36 + i], 1);
        pf[i] = __shfl_up(Mv[39 + i], 1);
    }
    if (lane == 0) {
        pA[0]=1.f; pA[1]=0.f; pA[2]=0.f; pA[3]=0.f; pA[4]=1.f; pA[5]=0.f;
        pA[6]=0.f; pA[7]=0.f; pA[8]=1.f;
        #pragma unroll
        for (int i = 0; i < 9; ++i) pC[i] = 0.f;
        pe[0]=pe[1]=pe[2]=0.f; pf[0]=pf[1]=pf[2]=0.f;
    }
    float px = pA[0]*p0x + pA[1]*p0y + pA[2]*p0z + pe[0];
    float py = pA[3]*p0x + pA[4]*p0y + pA[5]*p0z + pe[1];
    float pz = pA[6]*p0x + pA[7]*p0y + pA[8]*p0z + pe[2];
    float Wx = pC[0]*p0x + pC[1]*p0y + pC[2]*p0z + pf[0];
    float Wy = pC[3]*p0x + pC[4]*p0y + pC[5]*p0z + pf[1];
    float Wz = pC[6]*p0x + pC[7]*p0y + pC[8]*p0z + pf[2];

    // ---------------- P3: exact recurrence from entry state, write out -----
    s = s_in;
    for (int g = 0; g < 16; ++g) {
        float rbuf[36];
        #pragma unroll
        for (int j = 0; j < 9; ++j) {
            float4 v = rm4[g*9 + j];
            rbuf[4*j] = v.x; rbuf[4*j+1] = v.y; rbuf[4*j+2] = v.z; rbuf[4*j+3] = v.w;
        }
        float o[12];
        #pragma unroll
        for (int j = 0; j < 4; ++j) {
            const int k = g*4 + j;
            const unsigned sh = (unsigned)k & 31u;
            const unsigned lc = ((k < 32 ? lcLo : lcHi) >> sh) & 1u;
            const unsigned rc = ((k < 32 ? rcLo : rcHi) >> sh) & 1u;
            const unsigned ls = ((k < 32 ? lsLo : lsHi) >> sh) & 1u;
            const unsigned rs = ((k < 32 ? rsLo : rsHi) >> sh) & 1u;
            const int nwi  = (int)(ls | rs);
            const int c1   = (s == 1);
            const int c2   = (s == 2);
            const int hasc = (c1 & (int)lc) | (c2 & (int)rc);
            const int haso = (c1 & (int)rc) | (c2 & (int)lc);
            const int grab = nwi | ((hasc ^ 1) & haso);
            const int gi   = nwi ? (ls ? 0 : 1) : c1;
            const int new_s = grab ? gi + 1 : (hasc ? s : 0);

            const float* Rk = rbuf + 9*j;
            float2 ha = hd2[k*3+0], hb = hd2[k*3+1], hcp = hd2[k*3+2];
            if (grab) {
                const float hx = gi ? hb.y  : ha.x;
                const float hy = gi ? hcp.x : ha.y;
                const float hz = gi ? hcp.y : hb.x;
                const float vx = px - hx, vy = py - hy, vz = pz - hz;
                const float d2 = vx*vx + vy*vy + vz*vz;
                if (d2 > 1e-12f) {
                    Wx = Rk[0]*vx + Rk[3]*vy + Rk[6]*vz;
                    Wy = Rk[1]*vx + Rk[4]*vy + Rk[7]*vz;
                    Wz = Rk[2]*vx + Rk[5]*vy + Rk[8]*vz;
                } else {
                    Wx = 0.1f*Rk[6]; Wy = 0.1f*Rk[7]; Wz = 0.1f*Rk[8];
                }
            }
            if (new_s) {
                const int ci = new_s - 1;
                const float hx = ci ? hb.y  : ha.x;
                const float hy = ci ? hcp.x : ha.y;
                const float hz = ci ? hcp.y : hb.x;
                px = hx + Rk[0]*Wx + Rk[1]*Wy + Rk[2]*Wz;
                py = hy + Rk[3]*Wx + Rk[4]*Wy + Rk[5]*Wz;
                pz = hz + Rk[6]*Wx + Rk[7]*Wy + Rk[8]*Wz;
            }
            s = new_s;
            o[3*j+0] = px; o[3*j+1] = py; o[3*j+2] = pz;
        }
        float4* dst = ob4 + g*3;
        dst[0] = make_float4(o[0], o[1], o[2],  o[3]);
        dst[1] = make_float4(o[4], o[5], o[6],  o[7]);
        dst[2] = make_float4(o[8], o[9], o[10], o[11]);
    }
}

// ---------------- fallback (any T): round-3 wave-per-batch serial scan -----
#define CT 256
__global__ __launch_bounds__(64) void fk_scan_wave(
    const float* __restrict__ prob, const float* __restrict__ hands,
    const float* __restrict__ rotm, const float* __restrict__ tinit,
    float* __restrict__ out, int B, int T)
{
    __shared__ __align__(16) float sP[CT * 2];
    __shared__ __align__(16) float sH[CT * 8];
    __shared__ __align__(16) float sR[CT * 12];
    const int b = blockIdx.x, lane = threadIdx.x;
    const float* prB = prob  + (size_t)b * T * 2;
    const float* hdB = hands + (size_t)b * T * 6;
    const float* rmB = rotm  + (size_t)b * T * 9;
    float*       obB = out   + (size_t)b * T * 3;
    float px = tinit[3*b+0], py = tinit[3*b+1], pz = tinit[3*b+2];
    float Wx = 0.f, Wy = 0.f, Wz = 0.f;
    int cur = -1, prev_l = 0, prev_r = 0;
    for (int t0 = 0; t0 < T; t0 += CT) {
        const int n = (T - t0 < CT) ? (T - t0) : CT;
        for (int i = lane; i < n * 2; i += 64) sP[i] = prB[(size_t)t0*2 + i];
        for (int i = lane; i < n * 6; i += 64) {
            int s2 = i / 6, c = i - 6*s2; sH[8*s2+c] = hdB[(size_t)t0*6 + i];
        }
        for (int i = lane; i < n * 9; i += 64) {
            int s2 = i / 9, c = i - 9*s2; sR[12*s2+c] = rmB[(size_t)t0*9 + i];
        }
        __syncthreads();
        for (int k = 0; k < n; ++k) {
            const int t = t0 + k;
            const int rl = __builtin_amdgcn_readfirstlane(sP[2*k]   > 0.5f ? 1 : 0);
            const int rr = __builtin_amdgcn_readfirstlane(sP[2*k+1] > 0.5f ? 1 : 0);
            const int nz = (t != 0) ? 1 : 0;
            const int l_c = rl & nz, r_c = rr & nz;
            const int l_s = rl & (prev_l ^ 1) & nz, r_s = rr & (prev_r ^ 1) & nz;
            prev_l = rl; prev_r = rr;
            const int nw = l_s ? 0 : (r_s ? 1 : -1);
            const int hasc = ((cur==0)&l_c) | ((cur==1)&r_c);
            const int haso = ((cur==0)&r_c) | ((cur==1)&l_c);
            const int grab = (nw != -1) | ((hasc^1)&haso);
            const int new_cur = grab ? ((nw!=-1)?nw:(1-cur))
                                     : (((hasc^1)&(cur!=-1)) ? -1 : cur);
            if (new_cur != -1) {
                const float h0x=sH[8*k+0],h0y=sH[8*k+1],h0z=sH[8*k+2];
                const float h1x=sH[8*k+3],h1y=sH[8*k+4],h1z=sH[8*k+5];
                const float R0=sR[12*k+0],R1=sR[12*k+1],R2=sR[12*k+2];
                const float R3=sR[12*k+3],R4=sR[12*k+4],R5=sR[12*k+5];
                const float R6=sR[12*k+6],R7=sR[12*k+7],R8=sR[12*k+8];
                const float hx = new_cur ? h1x : h0x;
                const float hy = new_cur ? h1y : h0y;
                const float hz = new_cur ? h1z : h0z;
                if (grab) {
                    const float vx=px-hx, vy=py-hy, vz=pz-hz;
                    const float d2 = vx*vx+vy*vy+vz*vz;
                    if (d2 > 1e-12f) {
                        Wx = R0*vx+R3*vy+R6*vz; Wy = R1*vx+R4*vy+R7*vz; Wz = R2*vx+R5*vy+R8*vz;
                    } else { Wx = 0.1f*R6; Wy = 0.1f*R7; Wz = 0.1f*R8; }
                }
                px = hx + (R0*Wx+R1*Wy+R2*Wz);
                py = hy + (R3*Wx+R4*Wy+R5*Wz);
                pz = hz + (R6*Wx+R7*Wy+R8*Wz);
            }
            cur = new_cur;
            if (lane == 0) {
                obB[3*(size_t)t+0]=px; obB[3*(size_t)t+1]=py; obB[3*(size_t)t+2]=pz;
            }
        }
        __syncthreads();
    }
}

extern "C" void kernel_launch(void* const* d_in, const int* in_sizes, int n_in,
                              void* d_out, int out_size, void* d_ws, size_t ws_size,
                              hipStream_t stream) {
    const float* prob  = (const float*)d_in[0];
    const float* hands = (const float*)d_in[1];
    const float* rotm  = (const float*)d_in[2];
    const float* tinit = (const float*)d_in[3];
    float* out = (float*)d_out;

    const int B = in_sizes[3] / 3;
    const int T = in_sizes[0] / (B * 2);

    if (T == 4096) {
        hipLaunchKernelGGL(fk_scan_par, dim3(B), dim3(64), 0, stream,
                           prob, hands, rotm, tinit, out);
    } else {
        hipLaunchKernelGGL(fk_scan_wave, dim3(B), dim3(64), 0, stream,
                           prob, hands, rotm, tinit, out, B, T);
    }
}

// Round 6
// 83.956 us; speedup vs baseline: 15.9244x; 1.2433x over previous
//
#include <hip/hip_runtime.h>

// FK object-translation scan, round 6: T-parallel, typed affine maps, 4 waves.
// One block (256 threads) per batch; thread c owns steps [16c, 16c+16).
//  P1 : pack contact bits (16 per thread) + prev-step bit from global.
//  P1b: compose 3-state FSM maps; intra-wave Kogge-Stone + cross-wave LDS
//       combine -> exact entry state s_in per thread.
//  P2 : compose TYPED affine float maps: two outputs (p,W), each an affine
//       function of exactly ONE input (tag rp/rw in {p,w}) -- exact rep of
//       this map class. grab: Wmap <- R^T o pmap (p'~=p approx, as r5);
//       attach: pmap <- h + R o Wmap. 24 floats + 2 tags per map.
//  Affine KS scan (intra-wave) + cross-wave LDS combine -> (p_in, W_in).
//  P3 : exact replay of 16 steps from entry state, write outputs.
// Semantics identical to round-5 (passed, absmax 0.5 vs threshold 3.18).

#define FSM_ID 0x24  // identity: 0->0,1->1,2->2 (2 bits per state image)

__device__ __forceinline__ int fsm_compose(int f, int g) {  // g first, then f
    int r0 = (f >> (((g     ) & 3) << 1)) & 3;
    int r1 = (f >> (((g >> 2) & 3) << 1)) & 3;
    int r2 = (f >> (((g >> 4) & 3) << 1)) & 3;
    return r0 | (r1 << 2) | (r2 << 4);
}

// typed map layout: Mp[0..8], cp[9..11], Mw[12..20], cw[21..23]; tags rp,rw (0=p,1=w)
__device__ __forceinline__ void tmap_identity(float* m, int& rp, int& rw) {
    #pragma unroll
    for (int i = 0; i < 24; ++i) m[i] = 0.f;
    m[0] = m[4] = m[8] = 1.f;
    m[12] = m[16] = m[20] = 1.f;
    rp = 0; rw = 1;
}

__device__ __forceinline__ void tmap_compose(
    const float* Lm, int Lrp, int Lrw,
    const float* Em, int Erp, int Erw,
    float* Om, int& Orp, int& Orw)
{
    {   // p-output: L's p-map fed with E's output selected by Lrp
        float EM[9], Ec[3];
        #pragma unroll
        for (int i = 0; i < 9; ++i) EM[i] = Lrp ? Em[12+i] : Em[i];
        #pragma unroll
        for (int i = 0; i < 3; ++i) Ec[i] = Lrp ? Em[21+i] : Em[9+i];
        #pragma unroll
        for (int i = 0; i < 3; ++i) {
            #pragma unroll
            for (int j = 0; j < 3; ++j)
                Om[3*i+j] = Lm[3*i]*EM[j] + Lm[3*i+1]*EM[3+j] + Lm[3*i+2]*EM[6+j];
            Om[9+i] = Lm[3*i]*Ec[0] + Lm[3*i+1]*Ec[1] + Lm[3*i+2]*Ec[2] + Lm[9+i];
        }
        Orp = Lrp ? Erw : Erp;
    }
    {   // w-output
        float EM[9], Ec[3];
        #pragma unroll
        for (int i = 0; i < 9; ++i) EM[i] = Lrw ? Em[12+i] : Em[i];
        #pragma unroll
        for (int i = 0; i < 3; ++i) Ec[i] = Lrw ? Em[21+i] : Em[9+i];
        #pragma unroll
        for (int i = 0; i < 3; ++i) {
            #pragma unroll
            for (int j = 0; j < 3; ++j)
                Om[12+3*i+j] = Lm[12+3*i]*EM[j] + Lm[12+3*i+1]*EM[3+j] + Lm[12+3*i+2]*EM[6+j];
            Om[21+i] = Lm[12+3*i]*Ec[0] + Lm[12+3*i+1]*Ec[1] + Lm[12+3*i+2]*Ec[2] + Lm[21+i];
        }
        Orw = Lrw ? Erw : Erp;
    }
}

__global__ __launch_bounds__(256, 2) void fk_scan_par2(
    const float* __restrict__ prob,   // (B,4096,2)
    const float* __restrict__ hands,  // (B,4096,2,3)
    const float* __restrict__ rotm,   // (B,4096,3,3)
    const float* __restrict__ tinit,  // (B,3)
    float* __restrict__ out)          // (B,4096,3)
{
    const int b    = blockIdx.x;
    const int c    = threadIdx.x;     // chunk id 0..255, 16 steps each
    const int lane = c & 63;
    const int w    = c >> 6;

    __shared__ int   sFSM[4];
    __shared__ float sAm[4][24];
    __shared__ int   sAf[4];

    const float* prB = prob  + (size_t)b * 4096 * 2;
    const float* hdB = hands + (size_t)b * 4096 * 6;
    const float* rmB = rotm  + (size_t)b * 4096 * 9;
    float*       obB = out   + (size_t)b * 4096 * 3;

    const float4* pr4 = (const float4*)prB + c * 8;    // 16 steps * 2 / 4
    const float2* hd2 = (const float2*)hdB + c * 48;   // 16 steps * 6 / 2
    const float4* rm4 = (const float4*)rmB + c * 36;   // 16 steps * 9 / 4
    float4*       ob4 = (float4*)obB       + c * 12;   // 16 steps * 3 / 4

    // ---------------- P1: pack 16 contact bits ----------------
    unsigned lcB = 0, rcB = 0;
    #pragma unroll
    for (int i = 0; i < 8; ++i) {
        float4 v = pr4[i];
        lcB |= (unsigned)(v.x > 0.5f) << (2*i);
        rcB |= (unsigned)(v.y > 0.5f) << (2*i);
        lcB |= (unsigned)(v.z > 0.5f) << (2*i+1);
        rcB |= (unsigned)(v.w > 0.5f) << (2*i+1);
    }
    unsigned pL = 0, pR = 0;
    if (c) {
        float2 pv = *(const float2*)(prB + 32*c - 2);  // step 16c-1
        pL = pv.x > 0.5f ? 1u : 0u;
        pR = pv.y > 0.5f ? 1u : 0u;
    }
    unsigned lsB = lcB & ~((lcB << 1) | pL);
    unsigned rsB = rcB & ~((rcB << 1) | pR);
    if (c == 0) { lcB &= ~1u; rcB &= ~1u; lsB &= ~1u; rsB &= ~1u; } // t=0 forced false

    // ---------------- P1b: FSM compose + hierarchical scan ----------------
    int M = FSM_ID;
    #pragma unroll
    for (int k = 0; k < 16; ++k) {
        const unsigned lc = (lcB >> k) & 1u, rc = (rcB >> k) & 1u;
        const unsigned ls = (lsB >> k) & 1u, rs = (rsB >> k) & 1u;
        const int nwi = (int)(ls | rs);
        const int nwe = ls ? 1 : 2;
        const int e0  = lc ? 1 : (rc ? 2 : 0);
        const int e1  = rc ? 2 : (lc ? 1 : 0);
        const int mt  = nwi ? nwe * 0x15 : ((e0 << 2) | (e1 << 4));
        M = fsm_compose(mt, M);
    }
    #pragma unroll
    for (int d = 1; d < 64; d <<= 1) {
        int v  = __shfl_up(M, d);
        int cc = fsm_compose(M, v);
        M = (lane >= d) ? cc : M;
    }
    if (lane == 63) sFSM[w] = M;
    __syncthreads();
    int Pf = FSM_ID;
    for (int i = 0; i < w; ++i) Pf = fsm_compose(sFSM[i], Pf);
    int Me = __shfl_up(M, 1);
    if (lane == 0) Me = FSM_ID;
    const int s_in = fsm_compose(Me, Pf) & 3;   // applied to initial state 0 (cur=-1)

    // ---------------- P2: typed affine compose over 16 steps ----------------
    float Am[24]; int rp, rw;
    tmap_identity(Am, rp, rw);
    int s = s_in;
    #pragma unroll 1
    for (int g = 0; g < 4; ++g) {
        float rb[36];
        #pragma unroll
        for (int j = 0; j < 9; ++j) {
            float4 v = rm4[g*9 + j];
            rb[4*j]=v.x; rb[4*j+1]=v.y; rb[4*j+2]=v.z; rb[4*j+3]=v.w;
        }
        #pragma unroll
        for (int j = 0; j < 4; ++j) {
            const int k = 4*g + j;
            const unsigned lc=(lcB>>k)&1u, rc=(rcB>>k)&1u;
            const unsigned ls=(lsB>>k)&1u, rs=(rsB>>k)&1u;
            const int nwi  = (int)(ls|rs);
            const int c1 = (s==1), c2 = (s==2);
            const int hasc = (c1&(int)lc)|(c2&(int)rc);
            const int haso = (c1&(int)rc)|(c2&(int)lc);
            const int grab = nwi | ((hasc^1)&haso);
            const int gi   = nwi ? (ls?0:1) : c1;
            const int new_s= grab ? gi+1 : (hasc ? s : 0);
            const float* Rk = rb + 9*j;
            if (grab) {
                float2 ha=hd2[k*3], hb=hd2[k*3+1], hc=hd2[k*3+2];
                const float hx = gi?hb.y:ha.x, hy = gi?hc.x:ha.y, hz = gi?hc.y:hb.x;
                // Wmap <- R^T o pmap; cw = R^T (cp - h); rw = rp  (p'~=p approx)
                float t[9];
                #pragma unroll
                for (int i2=0;i2<3;++i2)
                    #pragma unroll
                    for (int j2=0;j2<3;++j2)
                        t[3*i2+j2] = Rk[i2]*Am[j2] + Rk[3+i2]*Am[3+j2] + Rk[6+i2]*Am[6+j2];
                const float ex=Am[9]-hx, ey=Am[10]-hy, ez=Am[11]-hz;
                Am[21] = Rk[0]*ex + Rk[3]*ey + Rk[6]*ez;
                Am[22] = Rk[1]*ex + Rk[4]*ey + Rk[7]*ez;
                Am[23] = Rk[2]*ex + Rk[5]*ey + Rk[8]*ez;
                #pragma unroll
                for (int i2=0;i2<9;++i2) Am[12+i2] = t[i2];
                rw = rp;
            } else if (new_s) {
                float2 ha=hd2[k*3], hb=hd2[k*3+1], hc=hd2[k*3+2];
                const int ci = new_s - 1;
                const float hx = ci?hb.y:ha.x, hy = ci?hc.x:ha.y, hz = ci?hc.y:hb.x;
                // pmap <- h + R o Wmap; rp = rw
                float t[9];
                #pragma unroll
                for (int i2=0;i2<3;++i2)
                    #pragma unroll
                    for (int j2=0;j2<3;++j2)
                        t[3*i2+j2] = Rk[3*i2]*Am[12+j2] + Rk[3*i2+1]*Am[15+j2] + Rk[3*i2+2]*Am[18+j2];
                const float e0_ = hx + Rk[0]*Am[21] + Rk[1]*Am[22] + Rk[2]*Am[23];
                const float e1_ = hy + Rk[3]*Am[21] + Rk[4]*Am[22] + Rk[5]*Am[23];
                const float e2_ = hz + Rk[6]*Am[21] + Rk[7]*Am[22] + Rk[8]*Am[23];
                #pragma unroll
                for (int i2=0;i2<9;++i2) Am[i2] = t[i2];
                Am[9]=e0_; Am[10]=e1_; Am[11]=e2_;
                rp = rw;
            }
            s = new_s;
        }
    }

    // ---------------- affine hierarchical scan ----------------
    #pragma unroll 1
    for (int d = 1; d < 64; d <<= 1) {
        float Em[24];
        #pragma unroll
        for (int i = 0; i < 24; ++i) Em[i] = __shfl_up(Am[i], d);
        const int Ef = __shfl_up(rp | (rw<<1), d);
        float Om[24]; int orp, orw;
        tmap_compose(Am, rp, rw, Em, Ef&1, (Ef>>1)&1, Om, orp, orw);
        const bool act = (lane >= d);
        #pragma unroll
        for (int i = 0; i < 24; ++i) Am[i] = act ? Om[i] : Am[i];
        rp = act ? orp : rp;
        rw = act ? orw : rw;
    }
    if (lane == 63) {
        #pragma unroll
        for (int i = 0; i < 24; ++i) sAm[w][i] = Am[i];
        sAf[w] = rp | (rw<<1);
    }
    __syncthreads();
    float Pm[24]; int Prp, Prw;
    tmap_identity(Pm, Prp, Prw);
    for (int i = 0; i < w; ++i) {           // wave prefix: P <- total(i) o P
        float Lm[24];
        #pragma unroll
        for (int q = 0; q < 24; ++q) Lm[q] = sAm[i][q];
        const int f = sAf[i];
        float Tm[24]; int trp, trw;
        tmap_compose(Lm, f&1, (f>>1)&1, Pm, Prp, Prw, Tm, trp, trw);
        #pragma unroll
        for (int q = 0; q < 24; ++q) Pm[q] = Tm[q];
        Prp = trp; Prw = trw;
    }
    float Xm[24];
    #pragma unroll
    for (int i = 0; i < 24; ++i) Xm[i] = __shfl_up(Am[i], 1);
    int Xf = __shfl_up(rp | (rw<<1), 1);
    int Xrp = Xf & 1, Xrw = (Xf >> 1) & 1;
    if (lane == 0) tmap_identity(Xm, Xrp, Xrw);
    float Gm[24]; int Grp, Grw;
    tmap_compose(Xm, Xrp, Xrw, Pm, Prp, Prw, Gm, Grp, Grw);

    // entry state: apply global-exclusive map to (p0 = tinit, W0 = 0)
    const float p0x = tinit[3*b], p0y = tinit[3*b+1], p0z = tinit[3*b+2];
    float px, py, pz, Wx, Wy, Wz;
    if (Grp == 0) {
        px = Gm[0]*p0x + Gm[1]*p0y + Gm[2]*p0z + Gm[9];
        py = Gm[3]*p0x + Gm[4]*p0y + Gm[5]*p0z + Gm[10];
        pz = Gm[6]*p0x + Gm[7]*p0y + Gm[8]*p0z + Gm[11];
    } else { px = Gm[9]; py = Gm[10]; pz = Gm[11]; }
    if (Grw == 0) {
        Wx = Gm[12]*p0x + Gm[13]*p0y + Gm[14]*p0z + Gm[21];
        Wy = Gm[15]*p0x + Gm[16]*p0y + Gm[17]*p0z + Gm[22];
        Wz = Gm[18]*p0x + Gm[19]*p0y + Gm[20]*p0z + Gm[23];
    } else { Wx = Gm[21]; Wy = Gm[22]; Wz = Gm[23]; }

    // ---------------- P3: exact replay + output ----------------
    s = s_in;
    #pragma unroll 1
    for (int g = 0; g < 4; ++g) {
        float rb[36];
        #pragma unroll
        for (int j = 0; j < 9; ++j) {
            float4 v = rm4[g*9 + j];
            rb[4*j]=v.x; rb[4*j+1]=v.y; rb[4*j+2]=v.z; rb[4*j+3]=v.w;
        }
        float o[12];
        #pragma unroll
        for (int j = 0; j < 4; ++j) {
            const int k = 4*g + j;
            const unsigned lc=(lcB>>k)&1u, rc=(rcB>>k)&1u;
            const unsigned ls=(lsB>>k)&1u, rs=(rsB>>k)&1u;
            const int nwi  = (int)(ls|rs);
            const int c1 = (s==1), c2 = (s==2);
            const int hasc = (c1&(int)lc)|(c2&(int)rc);
            const int haso = (c1&(int)rc)|(c2&(int)lc);
            const int grab = nwi | ((hasc^1)&haso);
            const int gi   = nwi ? (ls?0:1) : c1;
            const int new_s= grab ? gi+1 : (hasc ? s : 0);
            const float* Rk = rb + 9*j;
            float2 ha=hd2[k*3], hb=hd2[k*3+1], hc=hd2[k*3+2];
            if (grab) {
                const float hx = gi?hb.y:ha.x, hy = gi?hc.x:ha.y, hz = gi?hc.y:hb.x;
                const float vx = px-hx, vy = py-hy, vz = pz-hz;
                const float d2 = vx*vx + vy*vy + vz*vz;
                if (d2 > 1e-12f) {
                    Wx = Rk[0]*vx + Rk[3]*vy + Rk[6]*vz;
                    Wy = Rk[1]*vx + Rk[4]*vy + Rk[7]*vz;
                    Wz = Rk[2]*vx + Rk[5]*vy + Rk[8]*vz;
                } else {
                    Wx = 0.1f*Rk[6]; Wy = 0.1f*Rk[7]; Wz = 0.1f*Rk[8];
                }
            }
            if (new_s) {
                const int ci = new_s - 1;
                const float hx = ci?hb.y:ha.x, hy = ci?hc.x:ha.y, hz = ci?hc.y:hb.x;
                px = hx + Rk[0]*Wx + Rk[1]*Wy + Rk[2]*Wz;
                py = hy + Rk[3]*Wx + Rk[4]*Wy + Rk[5]*Wz;
                pz = hz + Rk[6]*Wx + Rk[7]*Wy + Rk[8]*Wz;
            }
            s = new_s;
            o[3*j+0]=px; o[3*j+1]=py; o[3*j+2]=pz;
        }
        ob4[g*3+0] = make_float4(o[0], o[1], o[2],  o[3]);
        ob4[g*3+1] = make_float4(o[4], o[5], o[6],  o[7]);
        ob4[g*3+2] = make_float4(o[8], o[9], o[10], o[11]);
    }
}

// ---------------- fallback (any T): wave-per-batch serial scan -----
#define CT 256
__global__ __launch_bounds__(64) void fk_scan_wave(
    const float* __restrict__ prob, const float* __restrict__ hands,
    const float* __restrict__ rotm, const float* __restrict__ tinit,
    float* __restrict__ out, int B, int T)
{
    __shared__ __align__(16) float sP[CT * 2];
    __shared__ __align__(16) float sH[CT * 8];
    __shared__ __align__(16) float sR[CT * 12];
    const int b = blockIdx.x, lane = threadIdx.x;
    const float* prB = prob  + (size_t)b * T * 2;
    const float* hdB = hands + (size_t)b * T * 6;
    const float* rmB = rotm  + (size_t)b * T * 9;
    float*       obB = out   + (size_t)b * T * 3;
    float px = tinit[3*b+0], py = tinit[3*b+1], pz = tinit[3*b+2];
    float Wx = 0.f, Wy = 0.f, Wz = 0.f;
    int cur = -1, prev_l = 0, prev_r = 0;
    for (int t0 = 0; t0 < T; t0 += CT) {
        const int n = (T - t0 < CT) ? (T - t0) : CT;
        for (int i = lane; i < n * 2; i += 64) sP[i] = prB[(size_t)t0*2 + i];
        for (int i = lane; i < n * 6; i += 64) {
            int s2 = i / 6, cc = i - 6*s2; sH[8*s2+cc] = hdB[(size_t)t0*6 + i];
        }
        for (int i = lane; i < n * 9; i += 64) {
            int s2 = i / 9, cc = i - 9*s2; sR[12*s2+cc] = rmB[(size_t)t0*9 + i];
        }
        __syncthreads();
        for (int k = 0; k < n; ++k) {
            const int t = t0 + k;
            const int rl = __builtin_amdgcn_readfirstlane(sP[2*k]   > 0.5f ? 1 : 0);
            const int rr = __builtin_amdgcn_readfirstlane(sP[2*k+1] > 0.5f ? 1 : 0);
            const int nz = (t != 0) ? 1 : 0;
            const int l_c = rl & nz, r_c = rr & nz;
            const int l_s = rl & (prev_l ^ 1) & nz, r_s = rr & (prev_r ^ 1) & nz;
            prev_l = rl; prev_r = rr;
            const int nw = l_s ? 0 : (r_s ? 1 : -1);
            const int hasc = ((cur==0)&l_c) | ((cur==1)&r_c);
            const int haso = ((cur==0)&r_c) | ((cur==1)&l_c);
            const int grab = (nw != -1) | ((hasc^1)&haso);
            const int new_cur = grab ? ((nw!=-1)?nw:(1-cur))
                                     : (((hasc^1)&(cur!=-1)) ? -1 : cur);
            if (new_cur != -1) {
                const float h0x=sH[8*k+0],h0y=sH[8*k+1],h0z=sH[8*k+2];
                const float h1x=sH[8*k+3],h1y=sH[8*k+4],h1z=sH[8*k+5];
                const float R0=sR[12*k+0],R1=sR[12*k+1],R2=sR[12*k+2];
                const float R3=sR[12*k+3],R4=sR[12*k+4],R5=sR[12*k+5];
                const float R6=sR[12*k+6],R7=sR[12*k+7],R8=sR[12*k+8];
                const float hx = new_cur ? h1x : h0x;
                const float hy = new_cur ? h1y : h0y;
                const float hz = new_cur ? h1z : h0z;
                if (grab) {
                    const float vx=px-hx, vy=py-hy, vz=pz-hz;
                    const float d2 = vx*vx+vy*vy+vz*vz;
                    if (d2 > 1e-12f) {
                        Wx = R0*vx+R3*vy+R6*vz; Wy = R1*vx+R4*vy+R7*vz; Wz = R2*vx+R5*vy+R8*vz;
                    } else { Wx = 0.1f*R6; Wy = 0.1f*R7; Wz = 0.1f*R8; }
                }
                px = hx + (R0*Wx+R1*Wy+R2*Wz);
                py = hy + (R3*Wx+R4*Wy+R5*Wz);
                pz = hz + (R6*Wx+R7*Wy+R8*Wz);
            }
            cur = new_cur;
            if (lane == 0) {
                obB[3*(size_t)t+0]=px; obB[3*(size_t)t+1]=py; obB[3*(size_t)t+2]=pz;
            }
        }
        __syncthreads();
    }
}

extern "C" void kernel_launch(void* const* d_in, const int* in_sizes, int n_in,
                              void* d_out, int out_size, void* d_ws, size_t ws_size,
                              hipStream_t stream) {
    const float* prob  = (const float*)d_in[0];
    const float* hands = (const float*)d_in[1];
    const float* rotm  = (const float*)d_in[2];
    const float* tinit = (const float*)d_in[3];
    float* out = (float*)d_out;

    const int B = in_sizes[3] / 3;
    const int T = in_sizes[0] / (B * 2);

    if (T == 4096) {
        hipLaunchKernelGGL(fk_scan_par2, dim3(B), dim3(256), 0, stream,
                           prob, hands, rotm, tinit, out);
    } else {
        hipLaunchKernelGGL(fk_scan_wave, dim3(B), dim3(64), 0, stream,
                           prob, hands, rotm, tinit, out, B, T);
    }
}

// Round 7
// 64.987 us; speedup vs baseline: 20.5725x; 1.2919x over previous
//
#include <hip/hip_runtime.h>

// FK object-translation scan, round 7: T-parallel, typed affine maps,
// 512 threads/block (8 waves), 8 steps/thread, batched unconditional loads.
//  P1 : pack 8 contact bits/thread (+ prev-step bit) -> lc/rc/ls/rs.
//  P1b: 3-state FSM map compose; intra-wave Kogge-Stone + 8-wave LDS combine
//       -> exact entry state s_in per thread.
//  P2 : typed affine map over (p, W=dir*dist): two outputs, each affine in
//       exactly ONE input (tags rp/rw). grab: Wmap <- R^T o pmap (p'~=p
//       approx, as r5/r6); attach: pmap <- h + R o Wmap. 24 floats + 2 tags.
//       Per 4-step group: ALL rotm/hands float4 loads issued as one batch
//       before the (divergent) compose -> one latency stall per group.
//  Affine KS scan + 8-wave LDS combine -> entry (p_in, W_in).
//  P3 : exact replay of 8 steps from entry state, write outputs.
// Algorithm identical to round-6 (passed, absmax 0.5 vs threshold 3.18).

#define FSM_ID 0x24  // identity: 0->0,1->1,2->2 (2 bits per state image)

__device__ __forceinline__ int fsm_compose(int f, int g) {  // g first, then f
    int r0 = (f >> (((g     ) & 3) << 1)) & 3;
    int r1 = (f >> (((g >> 2) & 3) << 1)) & 3;
    int r2 = (f >> (((g >> 4) & 3) << 1)) & 3;
    return r0 | (r1 << 2) | (r2 << 4);
}

// typed map: Mp[0..8], cp[9..11], Mw[12..20], cw[21..23]; tags rp,rw (0=p,1=w)
__device__ __forceinline__ void tmap_identity(float* m, int& rp, int& rw) {
    #pragma unroll
    for (int i = 0; i < 24; ++i) m[i] = 0.f;
    m[0] = m[4] = m[8] = 1.f;
    m[12] = m[16] = m[20] = 1.f;
    rp = 0; rw = 1;
}

__device__ __forceinline__ void tmap_compose(
    const float* Lm, int Lrp, int Lrw,
    const float* Em, int Erp, int Erw,
    float* Om, int& Orp, int& Orw)
{
    {   // p-output: L's p-map fed with E's output selected by Lrp
        float EM[9], Ec[3];
        #pragma unroll
        for (int i = 0; i < 9; ++i) EM[i] = Lrp ? Em[12+i] : Em[i];
        #pragma unroll
        for (int i = 0; i < 3; ++i) Ec[i] = Lrp ? Em[21+i] : Em[9+i];
        #pragma unroll
        for (int i = 0; i < 3; ++i) {
            #pragma unroll
            for (int j = 0; j < 3; ++j)
                Om[3*i+j] = Lm[3*i]*EM[j] + Lm[3*i+1]*EM[3+j] + Lm[3*i+2]*EM[6+j];
            Om[9+i] = Lm[3*i]*Ec[0] + Lm[3*i+1]*Ec[1] + Lm[3*i+2]*Ec[2] + Lm[9+i];
        }
        Orp = Lrp ? Erw : Erp;
    }
    {   // w-output
        float EM[9], Ec[3];
        #pragma unroll
        for (int i = 0; i < 9; ++i) EM[i] = Lrw ? Em[12+i] : Em[i];
        #pragma unroll
        for (int i = 0; i < 3; ++i) Ec[i] = Lrw ? Em[21+i] : Em[9+i];
        #pragma unroll
        for (int i = 0; i < 3; ++i) {
            #pragma unroll
            for (int j = 0; j < 3; ++j)
                Om[12+3*i+j] = Lm[12+3*i]*EM[j] + Lm[12+3*i+1]*EM[3+j] + Lm[12+3*i+2]*EM[6+j];
            Om[21+i] = Lm[12+3*i]*Ec[0] + Lm[12+3*i+1]*Ec[1] + Lm[12+3*i+2]*Ec[2] + Lm[21+i];
        }
        Orw = Lrw ? Erw : Erp;
    }
}

__global__ __launch_bounds__(512, 4) void fk_scan_par3(
    const float* __restrict__ prob,   // (B,4096,2)
    const float* __restrict__ hands,  // (B,4096,2,3)
    const float* __restrict__ rotm,   // (B,4096,3,3)
    const float* __restrict__ tinit,  // (B,3)
    float* __restrict__ out)          // (B,4096,3)
{
    const int b    = blockIdx.x;
    const int c    = threadIdx.x;     // chunk id 0..511, 8 steps each
    const int lane = c & 63;
    const int w    = c >> 6;          // wave 0..7

    __shared__ int   sFSM[8];
    __shared__ float sAm[8][24];
    __shared__ int   sAf[8];

    const float* prB = prob  + (size_t)b * 4096 * 2;
    const float* hdB = hands + (size_t)b * 4096 * 6;
    const float* rmB = rotm  + (size_t)b * 4096 * 9;
    float*       obB = out   + (size_t)b * 4096 * 3;

    const float4* pr4 = (const float4*)prB + c * 4;    // 8 steps * 2 / 4
    const float4* hd4 = (const float4*)hdB + c * 12;   // 8 steps * 6 / 4
    const float4* rm4 = (const float4*)rmB + c * 18;   // 8 steps * 9 / 4
    float4*       ob4 = (float4*)obB       + c * 6;    // 8 steps * 3 / 4

    // ---------------- P1: pack 8 contact bits ----------------
    unsigned lcB = 0, rcB = 0;
    #pragma unroll
    for (int i = 0; i < 4; ++i) {
        float4 v = pr4[i];
        lcB |= (unsigned)(v.x > 0.5f) << (2*i);
        rcB |= (unsigned)(v.y > 0.5f) << (2*i);
        lcB |= (unsigned)(v.z > 0.5f) << (2*i+1);
        rcB |= (unsigned)(v.w > 0.5f) << (2*i+1);
    }
    unsigned pL = 0, pR = 0;
    if (c) {
        float2 pv = *(const float2*)(prB + 16*c - 2);  // step 8c-1
        pL = pv.x > 0.5f ? 1u : 0u;
        pR = pv.y > 0.5f ? 1u : 0u;
    }
    unsigned lsB = lcB & ~((lcB << 1) | pL);
    unsigned rsB = rcB & ~((rcB << 1) | pR);
    if (c == 0) { lcB &= ~1u; rcB &= ~1u; lsB &= ~1u; rsB &= ~1u; } // t=0 forced false

    // ---------------- P1b: FSM compose + hierarchical scan ----------------
    int M = FSM_ID;
    #pragma unroll
    for (int k = 0; k < 8; ++k) {
        const unsigned lc = (lcB >> k) & 1u, rc = (rcB >> k) & 1u;
        const unsigned ls = (lsB >> k) & 1u, rs = (rsB >> k) & 1u;
        const int nwi = (int)(ls | rs);
        const int nwe = ls ? 1 : 2;
        const int e0  = lc ? 1 : (rc ? 2 : 0);
        const int e1  = rc ? 2 : (lc ? 1 : 0);
        const int mt  = nwi ? nwe * 0x15 : ((e0 << 2) | (e1 << 4));
        M = fsm_compose(mt, M);
    }
    #pragma unroll
    for (int d = 1; d < 64; d <<= 1) {
        int v  = __shfl_up(M, d);
        int cc = fsm_compose(M, v);
        M = (lane >= d) ? cc : M;
    }
    if (lane == 63) sFSM[w] = M;
    __syncthreads();
    int Pf = FSM_ID;
    for (int i = 0; i < w; ++i) Pf = fsm_compose(sFSM[i], Pf);
    int Me = __shfl_up(M, 1);
    if (lane == 0) Me = FSM_ID;
    const int s_in = fsm_compose(Me, Pf) & 3;   // applied to initial state 0 (cur=-1)

    // ---------------- P2: typed affine compose over 8 steps ----------------
    float Am[24]; int rp, rw;
    tmap_identity(Am, rp, rw);
    int s = s_in;
    #pragma unroll
    for (int g = 0; g < 2; ++g) {
        // batched, unconditional group loads (one latency stall per group)
        float rb[36], hb[24];
        #pragma unroll
        for (int j = 0; j < 9; ++j) {
            float4 v = rm4[g*9 + j];
            rb[4*j]=v.x; rb[4*j+1]=v.y; rb[4*j+2]=v.z; rb[4*j+3]=v.w;
        }
        #pragma unroll
        for (int j = 0; j < 6; ++j) {
            float4 v = hd4[g*6 + j];
            hb[4*j]=v.x; hb[4*j+1]=v.y; hb[4*j+2]=v.z; hb[4*j+3]=v.w;
        }
        #pragma unroll
        for (int j = 0; j < 4; ++j) {
            const int k = 4*g + j;
            const unsigned lc=(lcB>>k)&1u, rc=(rcB>>k)&1u;
            const unsigned ls=(lsB>>k)&1u, rs=(rsB>>k)&1u;
            const int nwi  = (int)(ls|rs);
            const int c1 = (s==1), c2 = (s==2);
            const int hasc = (c1&(int)lc)|(c2&(int)rc);
            const int haso = (c1&(int)rc)|(c2&(int)lc);
            const int grab = nwi | ((hasc^1)&haso);
            const int gi   = nwi ? (ls?0:1) : c1;
            const int new_s= grab ? gi+1 : (hasc ? s : 0);
            const float* Rk = rb + 9*j;
            const float* Hk = hb + 6*j;
            if (grab) {
                const float hx = gi?Hk[3]:Hk[0], hy = gi?Hk[4]:Hk[1], hz = gi?Hk[5]:Hk[2];
                // Wmap <- R^T o pmap; cw = R^T (cp - h); rw = rp  (p'~=p approx)
                float t[9];
                #pragma unroll
                for (int i2=0;i2<3;++i2)
                    #pragma unroll
                    for (int j2=0;j2<3;++j2)
                        t[3*i2+j2] = Rk[i2]*Am[j2] + Rk[3+i2]*Am[3+j2] + Rk[6+i2]*Am[6+j2];
                const float ex=Am[9]-hx, ey=Am[10]-hy, ez=Am[11]-hz;
                Am[21] = Rk[0]*ex + Rk[3]*ey + Rk[6]*ez;
                Am[22] = Rk[1]*ex + Rk[4]*ey + Rk[7]*ez;
                Am[23] = Rk[2]*ex + Rk[5]*ey + Rk[8]*ez;
                #pragma unroll
                for (int i2=0;i2<9;++i2) Am[12+i2] = t[i2];
                rw = rp;
            } else if (new_s) {
                const int ci = new_s - 1;
                const float hx = ci?Hk[3]:Hk[0], hy = ci?Hk[4]:Hk[1], hz = ci?Hk[5]:Hk[2];
                // pmap <- h + R o Wmap; rp = rw
                float t[9];
                #pragma unroll
                for (int i2=0;i2<3;++i2)
                    #pragma unroll
                    for (int j2=0;j2<3;++j2)
                        t[3*i2+j2] = Rk[3*i2]*Am[12+j2] + Rk[3*i2+1]*Am[15+j2] + Rk[3*i2+2]*Am[18+j2];
                const float e0_ = hx + Rk[0]*Am[21] + Rk[1]*Am[22] + Rk[2]*Am[23];
                const float e1_ = hy + Rk[3]*Am[21] + Rk[4]*Am[22] + Rk[5]*Am[23];
                const float e2_ = hz + Rk[6]*Am[21] + Rk[7]*Am[22] + Rk[8]*Am[23];
                #pragma unroll
                for (int i2=0;i2<9;++i2) Am[i2] = t[i2];
                Am[9]=e0_; Am[10]=e1_; Am[11]=e2_;
                rp = rw;
            }
            s = new_s;
        }
    }

    // ---------------- affine hierarchical scan ----------------
    #pragma unroll 1
    for (int d = 1; d < 64; d <<= 1) {
        float Em[24];
        #pragma unroll
        for (int i = 0; i < 24; ++i) Em[i] = __shfl_up(Am[i], d);
        const int Ef = __shfl_up(rp | (rw<<1), d);
        float Om[24]; int orp, orw;
        tmap_compose(Am, rp, rw, Em, Ef&1, (Ef>>1)&1, Om, orp, orw);
        const bool act = (lane >= d);
        #pragma unroll
        for (int i = 0; i < 24; ++i) Am[i] = act ? Om[i] : Am[i];
        rp = act ? orp : rp;
        rw = act ? orw : rw;
    }
    if (lane == 63) {
        #pragma unroll
        for (int i = 0; i < 24; ++i) sAm[w][i] = Am[i];
        sAf[w] = rp | (rw<<1);
    }
    __syncthreads();
    float Pm[24]; int Prp, Prw;
    tmap_identity(Pm, Prp, Prw);
    for (int i = 0; i < w; ++i) {           // wave prefix: P <- total(i) o P
        float Lm[24];
        #pragma unroll
        for (int q = 0; q < 24; ++q) Lm[q] = sAm[i][q];
        const int f = sAf[i];
        float Tm[24]; int trp, trw;
        tmap_compose(Lm, f&1, (f>>1)&1, Pm, Prp, Prw, Tm, trp, trw);
        #pragma unroll
        for (int q = 0; q < 24; ++q) Pm[q] = Tm[q];
        Prp = trp; Prw = trw;
    }
    float Xm[24];
    #pragma unroll
    for (int i = 0; i < 24; ++i) Xm[i] = __shfl_up(Am[i], 1);
    int Xf = __shfl_up(rp | (rw<<1), 1);
    int Xrp = Xf & 1, Xrw = (Xf >> 1) & 1;
    if (lane == 0) tmap_identity(Xm, Xrp, Xrw);
    float Gm[24]; int Grp, Grw;
    tmap_compose(Xm, Xrp, Xrw, Pm, Prp, Prw, Gm, Grp, Grw);

    // entry state: apply global-exclusive map to (p0 = tinit, W0 = 0)
    const float p0x = tinit[3*b], p0y = tinit[3*b+1], p0z = tinit[3*b+2];
    float px, py, pz, Wx, Wy, Wz;
    if (Grp == 0) {
        px = Gm[0]*p0x + Gm[1]*p0y + Gm[2]*p0z + Gm[9];
        py = Gm[3]*p0x + Gm[4]*p0y + Gm[5]*p0z + Gm[10];
        pz = Gm[6]*p0x + Gm[7]*p0y + Gm[8]*p0z + Gm[11];
    } else { px = Gm[9]; py = Gm[10]; pz = Gm[11]; }
    if (Grw == 0) {
        Wx = Gm[12]*p0x + Gm[13]*p0y + Gm[14]*p0z + Gm[21];
        Wy = Gm[15]*p0x + Gm[16]*p0y + Gm[17]*p0z + Gm[22];
        Wz = Gm[18]*p0x + Gm[19]*p0y + Gm[20]*p0z + Gm[23];
    } else { Wx = Gm[21]; Wy = Gm[22]; Wz = Gm[23]; }

    // ---------------- P3: exact replay + output ----------------
    s = s_in;
    #pragma unroll
    for (int g = 0; g < 2; ++g) {
        float rb[36], hb[24];
        #pragma unroll
        for (int j = 0; j < 9; ++j) {
            float4 v = rm4[g*9 + j];
            rb[4*j]=v.x; rb[4*j+1]=v.y; rb[4*j+2]=v.z; rb[4*j+3]=v.w;
        }
        #pragma unroll
        for (int j = 0; j < 6; ++j) {
            float4 v = hd4[g*6 + j];
            hb[4*j]=v.x; hb[4*j+1]=v.y; hb[4*j+2]=v.z; hb[4*j+3]=v.w;
        }
        float o[12];
        #pragma unroll
        for (int j = 0; j < 4; ++j) {
            const int k = 4*g + j;
            const unsigned lc=(lcB>>k)&1u, rc=(rcB>>k)&1u;
            const unsigned ls=(lsB>>k)&1u, rs=(rsB>>k)&1u;
            const int nwi  = (int)(ls|rs);
            const int c1 = (s==1), c2 = (s==2);
            const int hasc = (c1&(int)lc)|(c2&(int)rc);
            const int haso = (c1&(int)rc)|(c2&(int)lc);
            const int grab = nwi | ((hasc^1)&haso);
            const int gi   = nwi ? (ls?0:1) : c1;
            const int new_s= grab ? gi+1 : (hasc ? s : 0);
            const float* Rk = rb + 9*j;
            const float* Hk = hb + 6*j;
            if (grab) {
                const float hx = gi?Hk[3]:Hk[0], hy = gi?Hk[4]:Hk[1], hz = gi?Hk[5]:Hk[2];
                const float vx = px-hx, vy = py-hy, vz = pz-hz;
                const float d2 = vx*vx + vy*vy + vz*vz;
                if (d2 > 1e-12f) {
                    Wx = Rk[0]*vx + Rk[3]*vy + Rk[6]*vz;
                    Wy = Rk[1]*vx + Rk[4]*vy + Rk[7]*vz;
                    Wz = Rk[2]*vx + Rk[5]*vy + Rk[8]*vz;
                } else {
                    Wx = 0.1f*Rk[6]; Wy = 0.1f*Rk[7]; Wz = 0.1f*Rk[8];
                }
            }
            if (new_s) {
                const int ci = new_s - 1;
                const float hx = ci?Hk[3]:Hk[0], hy = ci?Hk[4]:Hk[1], hz = ci?Hk[5]:Hk[2];
                px = hx + Rk[0]*Wx + Rk[1]*Wy + Rk[2]*Wz;
                py = hy + Rk[3]*Wx + Rk[4]*Wy + Rk[5]*Wz;
                pz = hz + Rk[6]*Wx + Rk[7]*Wy + Rk[8]*Wz;
            }
            s = new_s;
            o[3*j+0]=px; o[3*j+1]=py; o[3*j+2]=pz;
        }
        ob4[g*3+0] = make_float4(o[0], o[1], o[2],  o[3]);
        ob4[g*3+1] = make_float4(o[4], o[5], o[6],  o[7]);
        ob4[g*3+2] = make_float4(o[8], o[9], o[10], o[11]);
    }
}

// ---------------- fallback (any T): wave-per-batch serial scan -----
#define CT 256
__global__ __launch_bounds__(64) void fk_scan_wave(
    const float* __restrict__ prob, const float* __restrict__ hands,
    const float* __restrict__ rotm, const float* __restrict__ tinit,
    float* __restrict__ out, int B, int T)
{
    __shared__ __align__(16) float sP[CT * 2];
    __shared__ __align__(16) float sH[CT * 8];
    __shared__ __align__(16) float sR[CT * 12];
    const int b = blockIdx.x, lane = threadIdx.x;
    const float* prB = prob  + (size_t)b * T * 2;
    const float* hdB = hands + (size_t)b * T * 6;
    const float* rmB = rotm  + (size_t)b * T * 9;
    float*       obB = out   + (size_t)b * T * 3;
    float px = tinit[3*b+0], py = tinit[3*b+1], pz = tinit[3*b+2];
    float Wx = 0.f, Wy = 0.f, Wz = 0.f;
    int cur = -1, prev_l = 0, prev_r = 0;
    for (int t0 = 0; t0 < T; t0 += CT) {
        const int n = (T - t0 < CT) ? (T - t0) : CT;
        for (int i = lane; i < n * 2; i += 64) sP[i] = prB[(size_t)t0*2 + i];
        for (int i = lane; i < n * 6; i += 64) {
            int s2 = i / 6, cc = i - 6*s2; sH[8*s2+cc] = hdB[(size_t)t0*6 + i];
        }
        for (int i = lane; i < n * 9; i += 64) {
            int s2 = i / 9, cc = i - 9*s2; sR[12*s2+cc] = rmB[(size_t)t0*9 + i];
        }
        __syncthreads();
        for (int k = 0; k < n; ++k) {
            const int t = t0 + k;
            const int rl = __builtin_amdgcn_readfirstlane(sP[2*k]   > 0.5f ? 1 : 0);
            const int rr = __builtin_amdgcn_readfirstlane(sP[2*k+1] > 0.5f ? 1 : 0);
            const int nz = (t != 0) ? 1 : 0;
            const int l_c = rl & nz, r_c = rr & nz;
            const int l_s = rl & (prev_l ^ 1) & nz, r_s = rr & (prev_r ^ 1) & nz;
            prev_l = rl; prev_r = rr;
            const int nw = l_s ? 0 : (r_s ? 1 : -1);
            const int hasc = ((cur==0)&l_c) | ((cur==1)&r_c);
            const int haso = ((cur==0)&r_c) | ((cur==1)&l_c);
            const int grab = (nw != -1) | ((hasc^1)&haso);
            const int new_cur = grab ? ((nw!=-1)?nw:(1-cur))
                                     : (((hasc^1)&(cur!=-1)) ? -1 : cur);
            if (new_cur != -1) {
                const float h0x=sH[8*k+0],h0y=sH[8*k+1],h0z=sH[8*k+2];
                const float h1x=sH[8*k+3],h1y=sH[8*k+4],h1z=sH[8*k+5];
                const float R0=sR[12*k+0],R1=sR[12*k+1],R2=sR[12*k+2];
                const float R3=sR[12*k+3],R4=sR[12*k+4],R5=sR[12*k+5];
                const float R6=sR[12*k+6],R7=sR[12*k+7],R8=sR[12*k+8];
                const float hx = new_cur ? h1x : h0x;
                const float hy = new_cur ? h1y : h0y;
                const float hz = new_cur ? h1z : h0z;
                if (grab) {
                    const float vx=px-hx, vy=py-hy, vz=pz-hz;
                    const float d2 = vx*vx+vy*vy+vz*vz;
                    if (d2 > 1e-12f) {
                        Wx = R0*vx+R3*vy+R6*vz; Wy = R1*vx+R4*vy+R7*vz; Wz = R2*vx+R5*vy+R8*vz;
                    } else { Wx = 0.1f*R6; Wy = 0.1f*R7; Wz = 0.1f*R8; }
                }
                px = hx + (R0*Wx+R1*Wy+R2*Wz);
                py = hy + (R3*Wx+R4*Wy+R5*Wz);
                pz = hz + (R6*Wx+R7*Wy+R8*Wz);
            }
            cur = new_cur;
            if (lane == 0) {
                obB[3*(size_t)t+0]=px; obB[3*(size_t)t+1]=py; obB[3*(size_t)t+2]=pz;
            }
        }
        __syncthreads();
    }
}

extern "C" void kernel_launch(void* const* d_in, const int* in_sizes, int n_in,
                              void* d_out, int out_size, void* d_ws, size_t ws_size,
                              hipStream_t stream) {
    const float* prob  = (const float*)d_in[0];
    const float* hands = (const float*)d_in[1];
    const float* rotm  = (const float*)d_in[2];
    const float* tinit = (const float*)d_in[3];
    float* out = (float*)d_out;

    const int B = in_sizes[3] / 3;
    const int T = in_sizes[0] / (B * 2);

    if (T == 4096) {
        hipLaunchKernelGGL(fk_scan_par3, dim3(B), dim3(512), 0, stream,
                           prob, hands, rotm, tinit, out);
    } else {
        hipLaunchKernelGGL(fk_scan_wave, dim3(B), dim3(64), 0, stream,
                           prob, hands, rotm, tinit, out, B, T);
    }
}